// Round 2
// baseline (19165.620 us; speedup 1.0000x reference)
//
#include <hip/hip_runtime.h>
#include <cmath>

#define EPS 1e-5f

__device__ __forceinline__ int reflect_idx(int p, int S) {
    if (p < 0) p = -p;
    if (p >= S) p = 2 * S - 2 - p;
    return p;
}

// Tiled direct conv, 'same' output, NCHW. Each thread computes VEC consecutive
// x-outputs (same b,oc,y). Each 256-thread block covers 256*VEC consecutive
// linear outputs -> one oc per block (requires (256*VEC) | H*W). Weights for
// that oc staged in LDS (dynamic smem = Cin*K*K*4 bytes).
// Input = concat(src1 [C1], src2 [C2]) at logical Hout x Wout.
// upsample: physical input is (Hout/2, Wout/2), nearest.
// reflect: reflect-pad at logical size, else zero-pad. act 1 = tanh.
template<int K, int VEC>
__global__ void conv_tiled(const float* __restrict__ src1, const float* __restrict__ src2,
                           int C1, int C2,
                           const float* __restrict__ w, const float* __restrict__ bias,
                           float* __restrict__ out,
                           int B, int Co, int Hout, int Wout,
                           int pad, int upsample, int reflect, int act)
{
    extern __shared__ float lds_w[];
    const int tid = threadIdx.x;
    const long long start = ((long long)blockIdx.x * blockDim.x + tid) * VEC;
    const int x0 = (int)(start % Wout);
    const int y  = (int)((start / Wout) % Hout);
    const int oc = (int)((start / ((long long)Wout * Hout)) % Co);
    const int b  = (int)(start / ((long long)Wout * Hout * Co));

    const int Cin = C1 + C2;
    const int Hin = upsample ? (Hout >> 1) : Hout;
    const int Win = upsample ? (Wout >> 1) : Wout;

    // stage this oc's weights into LDS (uniform oc across block)
    const int nw = Cin * K * K;
    const float* wrow = w + (size_t)oc * nw;
    for (int i = tid; i < nw; i += blockDim.x) lds_w[i] = wrow[i];
    __syncthreads();

    int iy[K]; bool vy[K];
#pragma unroll
    for (int t = 0; t < K; ++t) {
        int p = y - pad + t;
        if (reflect) { p = reflect_idx(p, Hout); vy[t] = true; }
        else vy[t] = (p >= 0) && (p < Hout);
        iy[t] = vy[t] ? (upsample ? (p >> 1) : p) : 0;
    }
    int xi[VEC + K - 1];
#pragma unroll
    for (int j = 0; j < VEC + K - 1; ++j) {
        int q = x0 - pad + j;
        if (reflect) { q = reflect_idx(q, Wout); xi[j] = upsample ? (q >> 1) : q; }
        else xi[j] = (q >= 0 && q < Wout) ? (upsample ? (q >> 1) : q) : -1;
    }

    float acc[VEC];
    const float bv = bias[oc];
#pragma unroll
    for (int v = 0; v < VEC; ++v) acc[v] = bv;

    for (int half = 0; half < 2; ++half) {
        const int Ch = half ? C2 : C1;
        if (Ch == 0) continue;
        const float* srcb = half ? (src2 + (size_t)b * C2 * Hin * Win)
                                 : (src1 + (size_t)b * C1 * Hin * Win);
        const int c0 = half ? C1 : 0;
        for (int c = 0; c < Ch; ++c) {
            const float* sc = srcb + (size_t)c * Hin * Win;
            const float* wb = &lds_w[(c0 + c) * K * K];
#pragma unroll
            for (int t = 0; t < K; ++t) {
                if (!vy[t]) continue;
                const float* row = sc + iy[t] * Win;
                float iv[VEC + K - 1];
#pragma unroll
                for (int j = 0; j < VEC + K - 1; ++j)
                    iv[j] = (xi[j] >= 0) ? row[xi[j]] : 0.f;
#pragma unroll
                for (int u = 0; u < K; ++u) {
                    const float wv = wb[t * K + u];
#pragma unroll
                    for (int v = 0; v < VEC; ++v)
                        acc[v] = fmaf(iv[u + v], wv, acc[v]);
                }
            }
        }
    }

    const size_t obase = (size_t)start;
#pragma unroll
    for (int v = 0; v < VEC; ++v) {
        float o = acc[v];
        if (act == 1) o = tanhf(o);
        out[obase + v] = o;
    }
}

// InstanceNorm over HW per (b,c) slice. One block per (b,c). In-place safe.
__global__ void inorm_kernel(const float* __restrict__ in, float* __restrict__ out,
                             const float* __restrict__ resid, int HW, int relu)
{
    int bc = blockIdx.x;
    const float* p = in + (size_t)bc * HW;
    float s = 0.f, q = 0.f;
    for (int i = threadIdx.x; i < HW; i += blockDim.x) {
        float v = p[i]; s += v; q += v * v;
    }
#pragma unroll
    for (int off = 32; off > 0; off >>= 1) {
        s += __shfl_down(s, off);
        q += __shfl_down(q, off);
    }
    __shared__ float ss[4], sq[4];
    __shared__ float mrs[2];
    int lane = threadIdx.x & 63, wv = threadIdx.x >> 6;
    if (lane == 0) { ss[wv] = s; sq[wv] = q; }
    __syncthreads();
    if (threadIdx.x == 0) {
        float S = 0.f, Q = 0.f;
        int nwv = blockDim.x >> 6;
        for (int i = 0; i < nwv; ++i) { S += ss[i]; Q += sq[i]; }
        float m = S / HW;
        float v = Q / HW - m * m;
        if (v < 0.f) v = 0.f;
        mrs[0] = m; mrs[1] = rsqrtf(v + EPS);
    }
    __syncthreads();
    float m = mrs[0], rs = mrs[1];
    float* o = out + (size_t)bc * HW;
    const float* r = resid ? resid + (size_t)bc * HW : nullptr;
    for (int i = threadIdx.x; i < HW; i += blockDim.x) {
        float v = (p[i] - m) * rs;
        if (relu) v = fmaxf(v, 0.f);
        if (r) v += r[i];
        o[i] = v;
    }
}

// Deformable conv 3x3, pad=1, Cin==Cout==C. One block = C threads, POS x-positions.
template<int C, int POS>
__global__ void deform_conv_kernel(const float* __restrict__ x, const float* __restrict__ om,
                                   const float* __restrict__ w, const float* __restrict__ bias,
                                   float* __restrict__ out, int B, int H, int W)
{
    int nxb = W / POS;
    int blk = blockIdx.x;
    int xb = blk % nxb;
    int y  = (blk / nxb) % H;
    int b  = blk / (nxb * H);
    int tid = threadIdx.x;

    __shared__ float val[POS][C * 9];
    __shared__ int   sy0[POS][9], sx0[POS][9];
    __shared__ float sdy[POS][9], sdx[POS][9], smk[POS][9];

    for (int t = tid; t < POS * 9; t += C) {
        int pos = t / 9, k = t % 9;
        int xx = xb * POS + pos;
        size_t base = ((size_t)b * 27) * H * W + (size_t)y * W + xx;
        float offy = om[base + (size_t)(2 * k) * H * W];
        float offx = om[base + (size_t)(2 * k + 1) * H * W];
        float mk   = om[base + (size_t)(18 + k) * H * W];
        mk = 1.f / (1.f + expf(-mk));
        float py = (float)(y - 1 + k / 3) + offy;
        float px = (float)(xx - 1 + k % 3) + offx;
        float fy = floorf(py), fx = floorf(px);
        sy0[pos][k] = (int)fy; sx0[pos][k] = (int)fx;
        sdy[pos][k] = py - fy; sdx[pos][k] = px - fx;
        smk[pos][k] = mk;
    }
    __syncthreads();

    const float* xbase = x + (size_t)b * C * H * W;
    for (int e = tid; e < POS * C * 9; e += C) {
        int k = e % 9;
        int c = (e / 9) % C;
        int pos = e / (9 * C);
        int y0 = sy0[pos][k], x0 = sx0[pos][k];
        float dy = sdy[pos][k], dx = sdx[pos][k], mk = smk[pos][k];
        const float* xc = xbase + (size_t)c * H * W;
        int y1 = y0 + 1, x1 = x0 + 1;
        bool by0 = (y0 >= 0) && (y0 < H), by1 = (y1 >= 0) && (y1 < H);
        bool bx0 = (x0 >= 0) && (x0 < W), bx1 = (x1 >= 0) && (x1 < W);
        float v00 = (by0 && bx0) ? xc[y0 * W + x0] : 0.f;
        float v01 = (by0 && bx1) ? xc[y0 * W + x1] : 0.f;
        float v10 = (by1 && bx0) ? xc[y1 * W + x0] : 0.f;
        float v11 = (by1 && bx1) ? xc[y1 * W + x1] : 0.f;
        float v = v00 * (1.f - dy) * (1.f - dx) + v01 * (1.f - dy) * dx
                + v10 * dy * (1.f - dx) + v11 * dy * dx;
        val[pos][c * 9 + k] = v * mk;
    }
    __syncthreads();

    int o = tid;
    float acc[POS];
#pragma unroll
    for (int p2 = 0; p2 < POS; ++p2) acc[p2] = bias[o];
    const float* wo = w + (size_t)o * C * 9;
    for (int ck = 0; ck < C * 9; ++ck) {
        float wv = wo[ck];
#pragma unroll
        for (int p2 = 0; p2 < POS; ++p2)
            acc[p2] = fmaf(val[p2][ck], wv, acc[p2]);
    }
#pragma unroll
    for (int p2 = 0; p2 < POS; ++p2) {
        int xx = xb * POS + p2;
        out[((size_t)(b * C + o) * H + y) * W + xx] = acc[p2];
    }
}

// Sum |om[:, 0:18, :, :]| into *acc (om has Ctot channels).
__global__ void abs_sum_kernel(const float* __restrict__ om, int B, int Ctot, int HW,
                               float* __restrict__ acc)
{
    long long total = (long long)B * 18 * HW;
    float s = 0.f;
    for (long long i = (long long)blockIdx.x * blockDim.x + threadIdx.x; i < total;
         i += (long long)gridDim.x * blockDim.x) {
        int pos = (int)(i % HW);
        int c   = (int)((i / HW) % 18);
        int b   = (int)(i / ((long long)18 * HW));
        s += fabsf(om[((size_t)(b * Ctot + c)) * HW + pos]);
    }
#pragma unroll
    for (int off = 32; off > 0; off >>= 1) s += __shfl_down(s, off);
    __shared__ float ws_[4];
    int lane = threadIdx.x & 63, wv = threadIdx.x >> 6;
    if (lane == 0) ws_[wv] = s;
    __syncthreads();
    if (threadIdx.x == 0) {
        float t = 0.f;
        int nw = blockDim.x >> 6;
        for (int i = 0; i < nw; ++i) t += ws_[i];
        atomicAdd(acc, t);
    }
}

__global__ void zero2_kernel(float* a) { if (threadIdx.x < 2) a[threadIdx.x] = 0.f; }

__global__ void finalize_kernel(const float* __restrict__ acc, float* __restrict__ out) {
    out[0] = 0.5f * (acc[0] / (4.f * 18.f * 128.f * 128.f)
                   + acc[1] / (4.f * 18.f * 64.f * 64.f));
}

extern "C" void kernel_launch(void* const* d_in, const int* in_sizes, int n_in,
                              void* d_out, int out_size, void* d_ws, size_t ws_size,
                              hipStream_t stream)
{
    const float* x      = (const float*)d_in[0];
    const float* skip1  = (const float*)d_in[1];
    const float* skip2  = (const float*)d_in[2];
    const float* res_w  = (const float*)d_in[3];
    const float* res_b  = (const float*)d_in[4];
    const float* w1     = (const float*)d_in[5];
    const float* b1     = (const float*)d_in[6];
    const float* w2     = (const float*)d_in[7];
    const float* b2     = (const float*)d_in[8];
    const float* w3     = (const float*)d_in[9];
    const float* b3     = (const float*)d_in[10];
    const float* off2_w = (const float*)d_in[11];
    const float* off2_b = (const float*)d_in[12];
    const float* dcn2_w = (const float*)d_in[13];
    const float* dcn2_b = (const float*)d_in[14];
    const float* off1_w = (const float*)d_in[15];
    const float* off1_b = (const float*)d_in[16];
    const float* dcn1_w = (const float*)d_in[17];
    const float* dcn1_b = (const float*)d_in[18];

    float* ws = (float*)d_ws;
    float* cur  = ws;              // (4,256,32,32)
    float* hbuf = ws + 1048576;    // (4,256,32,32)
    float* tbuf = ws + 2097152;    // (4,256,32,32)
    float* out1 = ws + 3145728;    // (4,128,64,64)
    float* om2  = ws + 5242880;    // (4,27,64,64)
    float* pre2 = ws + 5685248;    // (4,128,64,64)
    float* out2 = ws + 7782400;    // (4,64,128,128)
    float* om1  = ws + 11976704;   // (4,27,128,128)
    float* pre1 = ws + 13746176;   // (4,64,128,128)
    float* acc  = ws + 17940480;   // 2 floats
    if (ws_size < (size_t)17940482 * sizeof(float)) return;

    float* outp = (float*)d_out;

    zero2_kernel<<<dim3(1), dim3(64), 0, stream>>>(acc);

    // blocks for conv_tiled: total_outputs / (256*VEC)
    auto nbv = [](int total, int vec) { return dim3((unsigned)(total / (256 * vec))); };

    // ---- residual blocks (256ch @ 32x32), VEC=4 (H*W=1024) ----
    for (int i = 0; i < 2; ++i) {
        const float* src = (i == 0) ? x : cur;
        const float* wA = res_w + (size_t)(i * 2 + 0) * 256 * 256 * 9;
        const float* bA = res_b + (i * 2 + 0) * 256;
        const float* wB = res_w + (size_t)(i * 2 + 1) * 256 * 256 * 9;
        const float* bB = res_b + (i * 2 + 1) * 256;
        conv_tiled<3, 4><<<nbv(4*256*1024, 4), 256, 256*9*4, stream>>>(
            src, nullptr, 256, 0, wA, bA, tbuf, 4, 256, 32, 32, 1, 0, 1, 0);
        inorm_kernel<<<dim3(1024), dim3(256), 0, stream>>>(tbuf, hbuf, nullptr, 1024, 1);
        conv_tiled<3, 4><<<nbv(4*256*1024, 4), 256, 256*9*4, stream>>>(
            hbuf, nullptr, 256, 0, wB, bB, tbuf, 4, 256, 32, 32, 1, 0, 1, 0);
        inorm_kernel<<<dim3(1024), dim3(256), 0, stream>>>(tbuf, cur, src, 1024, 0);
    }

    // ---- up2 + refpad2 + conv5x5 (256->128) @64x64, IN+relu ----
    conv_tiled<5, 8><<<nbv(4*128*4096, 8), 256, 256*25*4, stream>>>(
        cur, nullptr, 256, 0, w1, b1, out1, 4, 128, 64, 64, 2, 1, 1, 0);
    inorm_kernel<<<dim3(512), dim3(256), 0, stream>>>(out1, out1, nullptr, 4096, 1);

    // ---- om2 = conv3x3 zero-pad on concat[out1, skip2] (256->27) @64x64 ----
    conv_tiled<3, 8><<<nbv(4*27*4096, 8), 256, 256*9*4, stream>>>(
        out1, skip2, 128, 128, off2_w, off2_b, om2, 4, 27, 64, 64, 1, 0, 0, 0);

    // ---- pre2 = deform_conv(skip2, om2) (128ch @64x64) ----
    deform_conv_kernel<128, 8><<<dim3(4*64*8), dim3(128), 0, stream>>>(
        skip2, om2, dcn2_w, dcn2_b, pre2, 4, 64, 64);

    // ---- up2 + refpad2 + conv5x5 on concat[pre2, out1] (256->64) @128x128, IN+relu ----
    conv_tiled<5, 8><<<nbv(4*64*16384, 8), 256, 256*25*4, stream>>>(
        pre2, out1, 128, 128, w2, b2, out2, 4, 64, 128, 128, 2, 1, 1, 0);
    inorm_kernel<<<dim3(256), dim3(256), 0, stream>>>(out2, out2, nullptr, 16384, 1);

    // ---- om1 = conv3x3 zero-pad on concat[out2, skip1] (128->27) @128x128 ----
    conv_tiled<3, 8><<<nbv(4*27*16384, 8), 256, 128*9*4, stream>>>(
        out2, skip1, 64, 64, off1_w, off1_b, om1, 4, 27, 128, 128, 1, 0, 0, 0);

    // ---- pre1 = deform_conv(skip1, om1) (64ch @128x128) ----
    deform_conv_kernel<64, 8><<<dim3(4*128*16), dim3(64), 0, stream>>>(
        skip1, om1, dcn1_w, dcn1_b, pre1, 4, 128, 128);

    // ---- conv7x7 refpad3 on concat[pre1, out2] (128->3) @128x128, tanh -> d_out ----
    conv_tiled<7, 4><<<nbv(4*3*16384, 4), 256, 128*49*4, stream>>>(
        pre1, out2, 64, 64, w3, b3, outp, 4, 3, 128, 128, 3, 0, 1, 1);

    // ---- offset_sum scalar ----
    abs_sum_kernel<<<dim3(256), dim3(256), 0, stream>>>(om1, 4, 27, 16384, acc + 0);
    abs_sum_kernel<<<dim3(256), dim3(256), 0, stream>>>(om2, 4, 27, 4096, acc + 1);
    finalize_kernel<<<dim3(1), dim3(1), 0, stream>>>(acc, outp + 196608);
}

// Round 3
// 5202.037 us; speedup vs baseline: 3.6843x; 3.6843x over previous
//
#include <hip/hip_runtime.h>
#include <cmath>

#define EPS 1e-5f

__device__ __forceinline__ int reflect_idx(int p, int S) {
    if (p < 0) p = -p;
    if (p >= S) p = 2 * S - 2 - p;
    return p;
}

// Transpose weights [Co][Cin][K*K] -> [Cin*K*K][Co] (oc contiguous).
__global__ void wtrans_kernel(const float* __restrict__ w, float* __restrict__ wt,
                              int Co, int Cin, int KK)
{
    int i = blockIdx.x * blockDim.x + threadIdx.x;
    int total = Co * Cin * KK;
    if (i >= total) return;
    int k  = i % KK;
    int c  = (i / KK) % Cin;
    int oc = i / (KK * Cin);
    wt[(c * KK + k) * Co + oc] = w[i];
}

// Tiled direct conv, 'same' output, NCHW, fp32.
// Block tile: TH rows x TW=XG*VEC cols x OCB=OG*OCT ocs. NT=TH*XG*OG threads.
// Thread: OCT ocs x VEC consecutive x (acc[OCT][VEC]).
// LDS: input patch [CCH][TH+K-1][TW+K-1 padded] + weights [CCH][K*K][OCB] (from wt, oc-contig).
// Input = concat(src1 [C1], src2 [C2]); upsample: physical input at half res (nearest);
// reflect: reflect-pad at logical size, else zero-pad. grid: x = B*NYT*NXT, y = oc groups.
template<int K, int TH, int XG, int VEC, int OG, int OCT, int CCH>
__global__ void conv_mod(const float* __restrict__ src1, const float* __restrict__ src2,
                         int C1, int C2,
                         const float* __restrict__ wt, const float* __restrict__ bias,
                         float* __restrict__ out,
                         int B, int Co, int Hout, int Wout, int upsample, int reflect)
{
    constexpr int TW  = XG * VEC;
    constexpr int OCB = OG * OCT;
    constexpr int PAD = K / 2;
    constexpr int PR  = TH + K - 1;
    constexpr int PW  = TW + K - 1;
    constexpr int PWP = (PW + 3) & ~3;
    constexpr int KK  = K * K;
    constexpr int NT  = TH * XG * OG;

    __shared__ float lds_in[CCH][PR][PWP];
    __shared__ float lds_w[CCH][KK][OCB];

    const int Cin = C1 + C2;
    const int Hin = upsample ? (Hout >> 1) : Hout;
    const int Win = upsample ? (Wout >> 1) : Wout;

    const int NXT = Wout / TW;
    const int NYT = Hout / TH;
    const int bx = blockIdx.x;
    const int xt = bx % NXT;
    const int yt = (bx / NXT) % NYT;
    const int b  = bx / (NXT * NYT);
    const int ocbase = blockIdx.y * OCB;

    const int tid = threadIdx.x;
    const int og = tid % OG;
    const int xg = (tid / OG) % XG;
    const int ty = tid / (OG * XG);

    const int y_out = yt * TH + ty;
    const int x0 = xt * TW + xg * VEC;
    const int oc0 = ocbase + og * OCT;

    float acc[OCT][VEC];
#pragma unroll
    for (int o = 0; o < OCT; ++o)
#pragma unroll
        for (int v = 0; v < VEC; ++v) acc[o][v] = 0.f;

    for (int cb = 0; cb < Cin; cb += CCH) {
        __syncthreads();
        // ---- stage input patch ----
        for (int i = tid; i < CCH * PR * PW; i += NT) {
            int px = i % PW;
            int pr = (i / PW) % PR;
            int c  = i / (PW * PR);
            int ly = yt * TH + pr - PAD;
            int lx = xt * TW + px - PAD;
            float v = 0.f;
            bool ok = true;
            if (reflect) { ly = reflect_idx(ly, Hout); lx = reflect_idx(lx, Wout); }
            else ok = (ly >= 0) && (ly < Hout) && (lx >= 0) && (lx < Wout);
            if (ok) {
                int sy = upsample ? (ly >> 1) : ly;
                int sx = upsample ? (lx >> 1) : lx;
                int cg = cb + c;
                const float* s = (cg < C1)
                    ? src1 + ((size_t)(b * C1 + cg)) * Hin * Win
                    : src2 + ((size_t)(b * C2 + (cg - C1))) * Hin * Win;
                v = s[sy * Win + sx];
            }
            lds_in[c][pr][px] = v;
        }
        // ---- stage weights (oc-contiguous global reads) ----
        for (int i = tid; i < CCH * KK * OCB; i += NT) {
            int oc = i % OCB;
            int kk = (i / OCB) % KK;
            int c  = i / (OCB * KK);
            int ocg = ocbase + oc;
            lds_w[c][kk][oc] = (ocg < Co)
                ? wt[((size_t)(cb + c) * KK + kk) * Co + ocg] : 0.f;
        }
        __syncthreads();
        // ---- compute ----
        for (int c = 0; c < CCH; ++c) {
#pragma unroll
            for (int r = 0; r < K; ++r) {
                float iv[VEC + K - 1];
#pragma unroll
                for (int j = 0; j < VEC + K - 1; ++j)
                    iv[j] = lds_in[c][ty + r][xg * VEC + j];
#pragma unroll
                for (int kx = 0; kx < K; ++kx) {
                    float wv[OCT];
#pragma unroll
                    for (int o = 0; o < OCT; ++o)
                        wv[o] = lds_w[c][r * K + kx][og * OCT + o];
#pragma unroll
                    for (int o = 0; o < OCT; ++o)
#pragma unroll
                        for (int v = 0; v < VEC; ++v)
                            acc[o][v] = fmaf(iv[kx + v], wv[o], acc[o][v]);
                }
            }
        }
    }

    // ---- epilogue ----
#pragma unroll
    for (int o = 0; o < OCT; ++o) {
        int oc = oc0 + o;
        if (oc >= Co) continue;
        float bv = bias[oc];
        size_t base = ((size_t)(b * Co + oc) * Hout + y_out) * Wout + x0;
#pragma unroll
        for (int v = 0; v < VEC; ++v)
            out[base + v] = acc[o][v] + bv;
    }
}

// Final conv: 7x7, reflect pad 3, concat(s1[64], s2[64]) @128x128 -> 3 ch, tanh.
// Thread per (b,y,x), 3 accumulators; weight indices thread-uniform (scalar loads).
__global__ void conv7_final(const float* __restrict__ s1, const float* __restrict__ s2,
                            const float* __restrict__ w, const float* __restrict__ bias,
                            float* __restrict__ out)
{
    const int H = 128, W = 128;
    int idx = blockIdx.x * blockDim.x + threadIdx.x;  // 4*128*128 threads
    int x = idx % W;
    int y = (idx / W) % H;
    int b = idx / (W * H);

    int xi[7], yi[7];
#pragma unroll
    for (int t = 0; t < 7; ++t) {
        yi[t] = reflect_idx(y - 3 + t, H);
        xi[t] = reflect_idx(x - 3 + t, W);
    }

    float a0 = bias[0], a1 = bias[1], a2 = bias[2];
    for (int half = 0; half < 2; ++half) {
        const float* src = half ? s2 : s1;
        const int cg0 = half ? 64 : 0;
        const float* sb = src + (size_t)b * 64 * H * W;
        for (int c = 0; c < 64; ++c) {
            const float* sc = sb + (size_t)c * H * W;
            const int cg = cg0 + c;
#pragma unroll
            for (int ky = 0; ky < 7; ++ky) {
                const float* row = sc + yi[ky] * W;
                float iv[7];
#pragma unroll
                for (int kx = 0; kx < 7; ++kx) iv[kx] = row[xi[kx]];
                const float* wr = w + (size_t)cg * 49 + ky * 7;  // + oc*128*49
#pragma unroll
                for (int kx = 0; kx < 7; ++kx) {
                    a0 = fmaf(iv[kx], wr[0 * 128 * 49 + kx], a0);
                    a1 = fmaf(iv[kx], wr[1 * 128 * 49 + kx], a1);
                    a2 = fmaf(iv[kx], wr[2 * 128 * 49 + kx], a2);
                }
            }
        }
    }
    size_t o = (size_t)b * 3 * H * W + (size_t)y * W + x;
    out[o]               = tanhf(a0);
    out[o + H * W]       = tanhf(a1);
    out[o + 2 * H * W]   = tanhf(a2);
}

// InstanceNorm over HW per (b,c). One block per (b,c). In-place safe.
__global__ void inorm_kernel(const float* __restrict__ in, float* __restrict__ out,
                             const float* __restrict__ resid, int HW, int relu)
{
    int bc = blockIdx.x;
    const float* p = in + (size_t)bc * HW;
    float s = 0.f, q = 0.f;
    for (int i = threadIdx.x; i < HW; i += blockDim.x) {
        float v = p[i]; s += v; q += v * v;
    }
#pragma unroll
    for (int off = 32; off > 0; off >>= 1) {
        s += __shfl_down(s, off);
        q += __shfl_down(q, off);
    }
    __shared__ float ss[4], sq[4];
    __shared__ float mrs[2];
    int lane = threadIdx.x & 63, wv = threadIdx.x >> 6;
    if (lane == 0) { ss[wv] = s; sq[wv] = q; }
    __syncthreads();
    if (threadIdx.x == 0) {
        float S = 0.f, Q = 0.f;
        int nwv = blockDim.x >> 6;
        for (int i = 0; i < nwv; ++i) { S += ss[i]; Q += sq[i]; }
        float m = S / HW;
        float v = Q / HW - m * m;
        if (v < 0.f) v = 0.f;
        mrs[0] = m; mrs[1] = rsqrtf(v + EPS);
    }
    __syncthreads();
    float m = mrs[0], rs = mrs[1];
    float* o = out + (size_t)bc * HW;
    const float* r = resid ? resid + (size_t)bc * HW : nullptr;
    for (int i = threadIdx.x; i < HW; i += blockDim.x) {
        float v = (p[i] - m) * rs;
        if (relu) v = fmaxf(v, 0.f);
        if (r) v += r[i];
        o[i] = v;
    }
}

// Deformable conv 3x3, pad=1, Cin==Cout==C. One block = C threads, POS x-positions.
template<int C, int POS>
__global__ void deform_conv_kernel(const float* __restrict__ x, const float* __restrict__ om,
                                   const float* __restrict__ w, const float* __restrict__ bias,
                                   float* __restrict__ out, int B, int H, int W)
{
    int nxb = W / POS;
    int blk = blockIdx.x;
    int xb = blk % nxb;
    int y  = (blk / nxb) % H;
    int b  = blk / (nxb * H);
    int tid = threadIdx.x;

    __shared__ float val[POS][C * 9];
    __shared__ int   sy0[POS][9], sx0[POS][9];
    __shared__ float sdy[POS][9], sdx[POS][9], smk[POS][9];

    for (int t = tid; t < POS * 9; t += C) {
        int pos = t / 9, k = t % 9;
        int xx = xb * POS + pos;
        size_t base = ((size_t)b * 27) * H * W + (size_t)y * W + xx;
        float offy = om[base + (size_t)(2 * k) * H * W];
        float offx = om[base + (size_t)(2 * k + 1) * H * W];
        float mk   = om[base + (size_t)(18 + k) * H * W];
        mk = 1.f / (1.f + expf(-mk));
        float py = (float)(y - 1 + k / 3) + offy;
        float px = (float)(xx - 1 + k % 3) + offx;
        float fy = floorf(py), fx = floorf(px);
        sy0[pos][k] = (int)fy; sx0[pos][k] = (int)fx;
        sdy[pos][k] = py - fy; sdx[pos][k] = px - fx;
        smk[pos][k] = mk;
    }
    __syncthreads();

    const float* xbase = x + (size_t)b * C * H * W;
    for (int e = tid; e < POS * C * 9; e += C) {
        int k = e % 9;
        int c = (e / 9) % C;
        int pos = e / (9 * C);
        int y0 = sy0[pos][k], x0 = sx0[pos][k];
        float dy = sdy[pos][k], dx = sdx[pos][k], mk = smk[pos][k];
        const float* xc = xbase + (size_t)c * H * W;
        int y1 = y0 + 1, x1 = x0 + 1;
        bool by0 = (y0 >= 0) && (y0 < H), by1 = (y1 >= 0) && (y1 < H);
        bool bx0 = (x0 >= 0) && (x0 < W), bx1 = (x1 >= 0) && (x1 < W);
        float v00 = (by0 && bx0) ? xc[y0 * W + x0] : 0.f;
        float v01 = (by0 && bx1) ? xc[y0 * W + x1] : 0.f;
        float v10 = (by1 && bx0) ? xc[y1 * W + x0] : 0.f;
        float v11 = (by1 && bx1) ? xc[y1 * W + x1] : 0.f;
        float v = v00 * (1.f - dy) * (1.f - dx) + v01 * (1.f - dy) * dx
                + v10 * dy * (1.f - dx) + v11 * dy * dx;
        val[pos][c * 9 + k] = v * mk;
    }
    __syncthreads();

    int o = tid;
    float acc[POS];
#pragma unroll
    for (int p2 = 0; p2 < POS; ++p2) acc[p2] = bias[o];
    const float* wo = w + (size_t)o * C * 9;
    for (int ck = 0; ck < C * 9; ++ck) {
        float wv = wo[ck];
#pragma unroll
        for (int p2 = 0; p2 < POS; ++p2)
            acc[p2] = fmaf(val[p2][ck], wv, acc[p2]);
    }
#pragma unroll
    for (int p2 = 0; p2 < POS; ++p2) {
        int xx = xb * POS + p2;
        out[((size_t)(b * C + o) * H + y) * W + xx] = acc[p2];
    }
}

// Sum |om[:, 0:18, :, :]| into *acc (om has Ctot channels).
__global__ void abs_sum_kernel(const float* __restrict__ om, int B, int Ctot, int HW,
                               float* __restrict__ acc)
{
    long long total = (long long)B * 18 * HW;
    float s = 0.f;
    for (long long i = (long long)blockIdx.x * blockDim.x + threadIdx.x; i < total;
         i += (long long)gridDim.x * blockDim.x) {
        int pos = (int)(i % HW);
        int c   = (int)((i / HW) % 18);
        int b   = (int)(i / ((long long)18 * HW));
        s += fabsf(om[((size_t)(b * Ctot + c)) * HW + pos]);
    }
#pragma unroll
    for (int off = 32; off > 0; off >>= 1) s += __shfl_down(s, off);
    __shared__ float ws_[4];
    int lane = threadIdx.x & 63, wv = threadIdx.x >> 6;
    if (lane == 0) ws_[wv] = s;
    __syncthreads();
    if (threadIdx.x == 0) {
        float t = 0.f;
        int nw = blockDim.x >> 6;
        for (int i = 0; i < nw; ++i) t += ws_[i];
        atomicAdd(acc, t);
    }
}

__global__ void zero2_kernel(float* a) { if (threadIdx.x < 2) a[threadIdx.x] = 0.f; }

__global__ void finalize_kernel(const float* __restrict__ acc, float* __restrict__ out) {
    out[0] = 0.5f * (acc[0] / (4.f * 18.f * 128.f * 128.f)
                   + acc[1] / (4.f * 18.f * 64.f * 64.f));
}

extern "C" void kernel_launch(void* const* d_in, const int* in_sizes, int n_in,
                              void* d_out, int out_size, void* d_ws, size_t ws_size,
                              hipStream_t stream)
{
    const float* x      = (const float*)d_in[0];
    const float* skip1  = (const float*)d_in[1];
    const float* skip2  = (const float*)d_in[2];
    const float* res_w  = (const float*)d_in[3];
    const float* res_b  = (const float*)d_in[4];
    const float* w1     = (const float*)d_in[5];
    const float* b1     = (const float*)d_in[6];
    const float* w2     = (const float*)d_in[7];
    const float* b2     = (const float*)d_in[8];
    const float* w3     = (const float*)d_in[9];
    const float* b3     = (const float*)d_in[10];
    const float* off2_w = (const float*)d_in[11];
    const float* off2_b = (const float*)d_in[12];
    const float* dcn2_w = (const float*)d_in[13];
    const float* dcn2_b = (const float*)d_in[14];
    const float* off1_w = (const float*)d_in[15];
    const float* off1_b = (const float*)d_in[16];
    const float* dcn1_w = (const float*)d_in[17];
    const float* dcn1_b = (const float*)d_in[18];

    float* ws = (float*)d_ws;
    float* cur  = ws;              // (4,256,32,32)
    float* hbuf = ws + 1048576;    // (4,256,32,32)
    float* tbuf = ws + 2097152;    // (4,256,32,32)
    float* out1 = ws + 3145728;    // (4,128,64,64)
    float* om2  = ws + 5242880;    // (4,27,64,64)
    float* pre2 = ws + 5685248;    // (4,128,64,64)
    float* out2 = ws + 7782400;    // (4,64,128,128)
    float* om1  = ws + 11976704;   // (4,27,128,128)
    float* pre1 = ws + 13746176;   // (4,64,128,128)
    float* acc  = ws + 17940480;   // 2 floats
    if (ws_size < (size_t)17940482 * sizeof(float)) return;

    // Transposed weights stashed in pre1's region (all consumed before
    // deform1 writes pre1).
    float* reswt = pre1;                 // 4 x 589824
    float* w1t   = pre1 + 2359296;       // 819200
    float* w2t   = pre1 + 3178496;       // 409600
    float* off2t = pre1 + 3588096;       // 62208
    float* off1t = pre1 + 3650304;       // 31104  (ends 3681408 < 4194304)

    float* outp = (float*)d_out;

    zero2_kernel<<<dim3(1), dim3(64), 0, stream>>>(acc);

    // ---- weight transposes ----
    for (int j = 0; j < 4; ++j)
        wtrans_kernel<<<dim3((589824 + 255) / 256), 256, 0, stream>>>(
            res_w + (size_t)j * 589824, reswt + (size_t)j * 589824, 256, 256, 9);
    wtrans_kernel<<<dim3((819200 + 255) / 256), 256, 0, stream>>>(w1, w1t, 128, 256, 25);
    wtrans_kernel<<<dim3((409600 + 255) / 256), 256, 0, stream>>>(w2, w2t, 64, 256, 25);
    wtrans_kernel<<<dim3((62208 + 255) / 256), 256, 0, stream>>>(off2_w, off2t, 27, 256, 9);
    wtrans_kernel<<<dim3((31104 + 255) / 256), 256, 0, stream>>>(off1_w, off1t, 27, 128, 9);

    // ---- residual blocks (256ch @ 32x32) ----
    // conv_mod<K=3,TH=4,XG=4,VEC=8,OG=8,OCT=4,CCH=8>: NT=128, TW=32, OCB=32
    for (int i = 0; i < 2; ++i) {
        const float* src = (i == 0) ? x : cur;
        const float* wA = reswt + (size_t)(i * 2 + 0) * 589824;
        const float* bA = res_b + (i * 2 + 0) * 256;
        const float* wB = reswt + (size_t)(i * 2 + 1) * 589824;
        const float* bB = res_b + (i * 2 + 1) * 256;
        conv_mod<3, 4, 4, 8, 8, 4, 8><<<dim3(32, 8), 128, 0, stream>>>(
            src, nullptr, 256, 0, wA, bA, tbuf, 4, 256, 32, 32, 0, 1);
        inorm_kernel<<<dim3(1024), dim3(256), 0, stream>>>(tbuf, hbuf, nullptr, 1024, 1);
        conv_mod<3, 4, 4, 8, 8, 4, 8><<<dim3(32, 8), 128, 0, stream>>>(
            hbuf, nullptr, 256, 0, wB, bB, tbuf, 4, 256, 32, 32, 0, 1);
        inorm_kernel<<<dim3(1024), dim3(256), 0, stream>>>(tbuf, cur, src, 1024, 0);
    }

    // ---- up2 + refpad2 + conv5x5 (256->128) @64x64, IN+relu ----
    // conv_mod<5,4,4,8,16,4,4>: NT=256, TW=32, OCB=64; grid (4*16*2, 2)
    conv_mod<5, 4, 4, 8, 16, 4, 4><<<dim3(128, 2), 256, 0, stream>>>(
        cur, nullptr, 256, 0, w1t, b1, out1, 4, 128, 64, 64, 1, 1);
    inorm_kernel<<<dim3(512), dim3(256), 0, stream>>>(out1, out1, nullptr, 4096, 1);

    // ---- om2 = conv3x3 zero-pad on concat[out1, skip2] (256->27) @64x64 ----
    // conv_mod<3,2,8,4,8,4,8>: NT=128, TW=32, OCB=32; grid (4*32*2, 1)
    conv_mod<3, 2, 8, 4, 8, 4, 8><<<dim3(256, 1), 128, 0, stream>>>(
        out1, skip2, 128, 128, off2t, off2_b, om2, 4, 27, 64, 64, 0, 0);

    // ---- pre2 = deform_conv(skip2, om2) (128ch @64x64) ----
    deform_conv_kernel<128, 8><<<dim3(4 * 64 * 8), dim3(128), 0, stream>>>(
        skip2, om2, dcn2_w, dcn2_b, pre2, 4, 64, 64);

    // ---- up2 + refpad2 + conv5x5 on concat[pre2, out1] (256->64) @128x128 ----
    conv_mod<5, 4, 4, 8, 16, 4, 4><<<dim3(512, 1), 256, 0, stream>>>(
        pre2, out1, 128, 128, w2t, b2, out2, 4, 64, 128, 128, 1, 1);
    inorm_kernel<<<dim3(256), dim3(256), 0, stream>>>(out2, out2, nullptr, 16384, 1);

    // ---- om1 = conv3x3 zero-pad on concat[out2, skip1] (128->27) @128x128 ----
    conv_mod<3, 2, 8, 4, 8, 4, 8><<<dim3(1024, 1), 128, 0, stream>>>(
        out2, skip1, 64, 64, off1t, off1_b, om1, 4, 27, 128, 128, 0, 0);

    // ---- pre1 = deform_conv(skip1, om1) (64ch @128x128) ----
    deform_conv_kernel<64, 8><<<dim3(4 * 128 * 16), dim3(64), 0, stream>>>(
        skip1, om1, dcn1_w, dcn1_b, pre1, 4, 128, 128);

    // ---- final conv7x7 refpad3 concat[pre1, out2] -> 3ch, tanh ----
    conv7_final<<<dim3(4 * 128 * 128 / 256), 256, 0, stream>>>(pre1, out2, w3, b3, outp);

    // ---- offset_sum scalar ----
    abs_sum_kernel<<<dim3(256), dim3(256), 0, stream>>>(om1, 4, 27, 16384, acc + 0);
    abs_sum_kernel<<<dim3(256), dim3(256), 0, stream>>>(om2, 4, 27, 4096, acc + 1);
    finalize_kernel<<<dim3(1), dim3(1), 0, stream>>>(acc, outp + 196608);
}

// Round 5
// 1467.141 us; speedup vs baseline: 13.0632x; 3.5457x over previous
//
#include <hip/hip_runtime.h>
#include <cmath>

#define EPS 1e-5f

typedef _Float16 half_t;
typedef __attribute__((ext_vector_type(8))) _Float16 half8;
typedef __attribute__((ext_vector_type(8))) short short8;
typedef __attribute__((ext_vector_type(4))) float f32x4;

__device__ __forceinline__ int reflect_idx(int p, int S) {
    if (p < 0) p = -p;
    if (p >= S) p = 2 * S - 2 - p;
    return p;
}
__device__ __forceinline__ float hlo(unsigned v) {
    return (float)__builtin_bit_cast(half_t, (unsigned short)(v & 0xffffu));
}
__device__ __forceinline__ float hhi(unsigned v) {
    return (float)__builtin_bit_cast(half_t, (unsigned short)(v >> 16));
}
__device__ __forceinline__ unsigned short hbits(float f) {
    return __builtin_bit_cast(unsigned short, (half_t)f);
}

// ---------------- weight transforms (fp32 -> fp16) ----------------
// conv weights [Co][Cin][KK] -> [KK][Cop][Cin], zero-padded oc in [Co,Cop)
__global__ void wtrans_conv(const float* __restrict__ w, half_t* __restrict__ wt,
                            int Co, int Cop, int Cin, int KK)
{
    int i = blockIdx.x * 256 + threadIdx.x;
    int total = KK * Cop * Cin;
    if (i >= total) return;
    int c  = i % Cin;
    int oc = (i / Cin) % Cop;
    int kk = i / (Cin * Cop);
    float v = (oc < Co) ? w[((size_t)oc * Cin + c) * KK + kk] : 0.f;
    wt[i] = (half_t)v;
}

// dcn weights [Co][Cin][9] -> [Co][k*Cin+c]
__global__ void wtrans_dcn(const float* __restrict__ w, half_t* __restrict__ wt,
                           int Co, int Cin)
{
    int i = blockIdx.x * 256 + threadIdx.x;
    int total = Co * 9 * Cin;
    if (i >= total) return;
    int c  = i % Cin;
    int k  = (i / Cin) % 9;
    int oc = i / (Cin * 9);
    wt[i] = (half_t)w[((size_t)oc * Cin + c) * 9 + k];
}

// ---------------- NCHW fp32 -> NHWC fp16 ----------------
__global__ void cvt_nchw_nhwc(const float* __restrict__ in, half_t* __restrict__ out,
                              int C, int H, int W, int total)
{
    int i = blockIdx.x * 256 + threadIdx.x;
    if (i >= total) return;
    int c = i % C;
    int x = (i / C) % W;
    int y = (i / (C * W)) % H;
    int b = i / (C * W * H);
    out[i] = (half_t)in[(((size_t)b * C + c) * H + y) * W + x];
}

// ---------------- MFMA implicit-GEMM conv ----------------
// Output tile 8x8 positions x COB ocs per block. 4 waves.
// Input NHWC fp16 = concat(in1[C1], in2[C2]). wt: [KK][Cop][Cin] fp16.
// UP: logical (Hout,Wout) from physical (Hout/2,Wout/2) nearest-upsample.
// REFLECT: reflect pad at logical size, else zero pad.
// outfmt: 0 = fp16 NHWC (stride Co), 1 = fp32 NCHW, 2 = fp32 NHWC. act 1 = tanh.
template<int K, int UP, int REFLECT, int COB>
__global__ __launch_bounds__(256)
void mfma_conv(const half_t* __restrict__ in1, const half_t* __restrict__ in2,
               int C1, int C2,
               const half_t* __restrict__ wt, const float* __restrict__ bias,
               void* __restrict__ outp,
               int Co, int Cop, int Hout, int Wout, int act, int outfmt)
{
    constexpr int TH = 8, TW = 8, PAD = K / 2;
    constexpr int PR = TH + K - 1, PW = TW + K - 1;
    constexpr int NPOS = PR * PW, KK = K * K;
    constexpr int NM = COB / 16;
    constexpr int NNW = NM;

    __shared__ short lds[NPOS * 40]; // 80B row stride (32ch + 8 pad shorts)

    const int Cin = C1 + C2;
    const int Hin = UP ? (Hout >> 1) : Hout;
    const int Win = UP ? (Wout >> 1) : Wout;
    const int NTX = Wout / TW, NTY = Hout / TH;

    const int tid = threadIdx.x;
    const int wv = tid >> 6, lane = tid & 63, l15 = lane & 15, kg = lane >> 4;
    const int bx = blockIdx.x;
    const int xt = (bx % NTX) * TW;
    const int yt = ((bx / NTX) % NTY) * TH;
    const int b  = bx / (NTX * NTY);
    const int ocb = blockIdx.y * COB;
    const int m  = wv % NM;
    const int n0 = (wv / NM) * NM;

    f32x4 acc[NNW];
#pragma unroll
    for (int t = 0; t < NNW; ++t) acc[t] = (f32x4){0.f, 0.f, 0.f, 0.f};

    int boff[NNW];
#pragma unroll
    for (int t = 0; t < NNW; ++t) {
        int pos = (n0 + t) * 16 + l15;
        boff[t] = ((pos >> 3) * PW + (pos & 7)) * 80 + kg * 16;
    }

    const half_t* wlane = wt + (size_t)(ocb + m * 16 + l15) * Cin + kg * 8;

    const int NCB = Cin >> 5;
    for (int cb = 0; cb < NCB; ++cb) {
        __syncthreads();
        // ---- stage input chunk (32 ch, channel-innermost) ----
        for (int e = tid; e < NPOS * 4; e += 256) {
            int p = e >> 2, g = e & 3;
            int py = p / PW, px = p % PW;
            int ly = yt + py - PAD, lx = xt + px - PAD;
            bool ok = true;
            if (REFLECT) { ly = reflect_idx(ly, Hout); lx = reflect_idx(lx, Wout); }
            else {
                ok = (ly >= 0) && (ly < Hout) && (lx >= 0) && (lx < Wout);
                if (!ok) { ly = 0; lx = 0; }
            }
            int sy = UP ? (ly >> 1) : ly;
            int sx = UP ? (lx >> 1) : lx;
            int gc = (cb << 5) + g * 8;
            const half_t* src; int Cl, c;
            if (gc < C1) { src = in1; Cl = C1; c = gc; }
            else         { src = in2; Cl = C2; c = gc - C1; }
            short8 v = (short8)0;
            if (ok) v = *(const short8*)(src + ((size_t)(b * Hin + sy) * Win + sx) * Cl + c);
            *(short8*)((char*)lds + p * 80 + g * 16) = v;
        }
        __syncthreads();
        const half_t* wc = wlane + (cb << 5);
#pragma unroll
        for (int kk = 0; kk < KK; ++kk) {
            half8 a = *(const half8*)(wc + (size_t)kk * Cop * Cin);
            const int sh = ((kk / K) * PW + (kk % K)) * 80;
#pragma unroll
            for (int t = 0; t < NNW; ++t) {
                half8 bb = *(const half8*)((char*)lds + boff[t] + sh);
                acc[t] = __builtin_amdgcn_mfma_f32_16x16x32_f16(a, bb, acc[t], 0, 0, 0);
            }
        }
    }

    // ---- epilogue ----
#pragma unroll
    for (int t = 0; t < NNW; ++t) {
        int pos = (n0 + t) * 16 + l15;
        int y = yt + (pos >> 3), x = xt + (pos & 7);
#pragma unroll
        for (int j = 0; j < 4; ++j) {
            int oc = ocb + m * 16 + kg * 4 + j;
            if (oc < Co) {
                float v = acc[t][j] + bias[oc];
                if (act) v = tanhf(v);
                if (outfmt == 0)
                    ((half_t*)outp)[((size_t)(b * Hout + y) * Wout + x) * Co + oc] = (half_t)v;
                else if (outfmt == 1)
                    ((float*)outp)[(((size_t)b * Co + oc) * Hout + y) * Wout + x] = v;
                else
                    ((float*)outp)[((size_t)(b * Hout + y) * Wout + x) * Co + oc] = v;
            }
        }
    }
}

// ---------------- MFMA deformable conv (gather fused into staging) ----------------
// xs: skip NHWC fp16 [B][H][W][C]; om: fp32 NCHW [B][27][H][W];
// wtd: [Co][9*C] fp16 (kidx = k*C+c); out fp16 NHWC stride Co. Co%32==0.
template<int C>
__global__ __launch_bounds__(256)
void mfma_dcn(const half_t* __restrict__ xs, const float* __restrict__ om,
              const half_t* __restrict__ wtd, const float* __restrict__ bias,
              half_t* __restrict__ outb, int Co, int H, int W)
{
    __shared__ short lds[64 * 40];
    __shared__ int   sy0[64], sx0[64];
    __shared__ float sdy[64], sdx[64], smk[64];

    const int NTX = W / 8, NTY = H / 8;
    const int tid = threadIdx.x;
    const int wv = tid >> 6, lane = tid & 63, l15 = lane & 15, kg = lane >> 4;
    const int bx = blockIdx.x;
    const int xt = (bx % NTX) * 8;
    const int yt = ((bx / NTX) % NTY) * 8;
    const int b  = bx / (NTX * NTY);
    const int ocb = blockIdx.y * 32;
    const int m = wv & 1, n0 = (wv >> 1) * 2;
    const int HW = H * W;

    f32x4 acc[2];
    acc[0] = (f32x4){0.f, 0.f, 0.f, 0.f};
    acc[1] = (f32x4){0.f, 0.f, 0.f, 0.f};
    int boff[2];
#pragma unroll
    for (int t = 0; t < 2; ++t)
        boff[t] = ((n0 + t) * 16 + l15) * 80 + kg * 16;

    const half_t* wlane = wtd + (size_t)(ocb + m * 16 + l15) * (9 * C) + kg * 8;

    const int NCB = (9 * C) >> 5;
    for (int cb = 0; cb < NCB; ++cb) {
        const int kidx0 = cb << 5;
        const int k = kidx0 / C, c0 = kidx0 % C;
        __syncthreads();
        if (tid < 64) {
            int pos = tid;
            int y = yt + (pos >> 3), x = xt + (pos & 7);
            size_t obase = (size_t)b * 27 * HW + (size_t)y * W + x;
            float offy = om[obase + (size_t)(2 * k) * HW];
            float offx = om[obase + (size_t)(2 * k + 1) * HW];
            float ml   = om[obase + (size_t)(18 + k) * HW];
            float mk = 1.f / (1.f + expf(-ml));
            float py = (float)(y - 1 + k / 3) + offy;
            float px = (float)(x - 1 + k % 3) + offx;
            float fy = floorf(py), fx = floorf(px);
            sy0[pos] = (int)fy; sx0[pos] = (int)fx;
            sdy[pos] = py - fy; sdx[pos] = px - fx; smk[pos] = mk;
        }
        __syncthreads();
        for (int u = tid; u < 1024; u += 256) {
            int pos = u >> 4, cp = u & 15;
            int c = c0 + cp * 2;
            int y0 = sy0[pos], x0 = sx0[pos];
            float dy = sdy[pos], dx = sdx[pos], mk = smk[pos];
            int y1 = y0 + 1, x1 = x0 + 1;
            float w00 = (1.f - dy) * (1.f - dx) * mk;
            float w01 = (1.f - dy) * dx * mk;
            float w10 = dy * (1.f - dx) * mk;
            float w11 = dy * dx * mk;
            bool vy0 = (y0 >= 0) && (y0 < H), vy1 = (y1 >= 0) && (y1 < H);
            bool vx0 = (x0 >= 0) && (x0 < W), vx1 = (x1 >= 0) && (x1 < W);
            if (!(vy0 && vx0)) w00 = 0.f;
            if (!(vy0 && vx1)) w01 = 0.f;
            if (!(vy1 && vx0)) w10 = 0.f;
            if (!(vy1 && vx1)) w11 = 0.f;
            int yc0 = min(max(y0, 0), H - 1), yc1 = min(max(y1, 0), H - 1);
            int xc0 = min(max(x0, 0), W - 1), xc1 = min(max(x1, 0), W - 1);
            const half_t* xb = xs + c;
            unsigned v00 = *(const unsigned*)(xb + ((size_t)(b * H + yc0) * W + xc0) * C);
            unsigned v01 = *(const unsigned*)(xb + ((size_t)(b * H + yc0) * W + xc1) * C);
            unsigned v10 = *(const unsigned*)(xb + ((size_t)(b * H + yc1) * W + xc0) * C);
            unsigned v11 = *(const unsigned*)(xb + ((size_t)(b * H + yc1) * W + xc1) * C);
            float lo = hlo(v00) * w00 + hlo(v01) * w01 + hlo(v10) * w10 + hlo(v11) * w11;
            float hi = hhi(v00) * w00 + hhi(v01) * w01 + hhi(v10) * w10 + hhi(v11) * w11;
            unsigned r = (unsigned)hbits(lo) | ((unsigned)hbits(hi) << 16);
            *(unsigned*)((char*)lds + pos * 80 + cp * 4) = r;
        }
        __syncthreads();
        half8 a = *(const half8*)(wlane + kidx0);
#pragma unroll
        for (int t = 0; t < 2; ++t) {
            half8 bb = *(const half8*)((char*)lds + boff[t]);
            acc[t] = __builtin_amdgcn_mfma_f32_16x16x32_f16(a, bb, acc[t], 0, 0, 0);
        }
    }

#pragma unroll
    for (int t = 0; t < 2; ++t) {
        int pos = (n0 + t) * 16 + l15;
        int y = yt + (pos >> 3), x = xt + (pos & 7);
#pragma unroll
        for (int j = 0; j < 4; ++j) {
            int oc = ocb + m * 16 + kg * 4 + j;
            float v = acc[t][j] + bias[oc];
            outb[((size_t)(b * H + y) * W + x) * Co + oc] = (half_t)v;
        }
    }
}

// ---------------- InstanceNorm (NHWC), 2 passes, templated input dtype ----------------
template<typename TI>
__global__ void inorm_p1(const TI* __restrict__ in, float* __restrict__ part,
                         int Cc, int HW, int NS)
{
    int bs = blockIdx.x; int s = bs % NS; int b = bs / NS;
    int tid = threadIdx.x;
    int c = tid % Cc, r = tid / Cc, G = 256 / Cc;
    int rows = HW / NS, p0 = s * rows;
    const TI* base = in + (size_t)b * HW * Cc;
    float sm = 0.f, sq = 0.f;
    for (int p = p0 + r; p < p0 + rows; p += G) {
        float v = (float)base[(size_t)p * Cc + c];
        sm += v; sq += v * v;
    }
    __shared__ float l1[256], l2[256];
    l1[tid] = sm; l2[tid] = sq;
    __syncthreads();
    if (r == 0) {
        for (int g = 1; g < G; ++g) { sm += l1[g * Cc + c]; sq += l2[g * Cc + c]; }
        part[((size_t)(b * NS + s) * Cc + c) * 2]     = sm;
        part[((size_t)(b * NS + s) * Cc + c) * 2 + 1] = sq;
    }
}

// out_h always written; out_f optional; resid: fp32 NHWC or fp32 NCHW (at most one).
template<typename TI>
__global__ void inorm_p2(const TI* __restrict__ in, half_t* __restrict__ out_h,
                         float* __restrict__ out_f,
                         const float* __restrict__ resid_nhwc,
                         const float* __restrict__ resid_nchw,
                         const float* __restrict__ part,
                         int Cc, int HW, int NS, int relu)
{
    int bs = blockIdx.x; int s = bs % NS; int b = bs / NS;
    int tid = threadIdx.x;
    int c = tid % Cc, r = tid / Cc, G = 256 / Cc;
    float S = 0.f, Q = 0.f;
    for (int s2 = 0; s2 < NS; ++s2) {
        S += part[((size_t)(b * NS + s2) * Cc + c) * 2];
        Q += part[((size_t)(b * NS + s2) * Cc + c) * 2 + 1];
    }
    float mmean = S / HW;
    float var = Q / HW - mmean * mmean;
    if (var < 0.f) var = 0.f;
    float rs = rsqrtf(var + EPS);
    int rows = HW / NS, p0 = s * rows;
    const TI* bi = in + (size_t)b * HW * Cc;
    for (int p = p0 + r; p < p0 + rows; p += G) {
        float v = ((float)bi[(size_t)p * Cc + c] - mmean) * rs;
        if (relu) v = fmaxf(v, 0.f);
        if (resid_nhwc) v += resid_nhwc[((size_t)b * HW + p) * Cc + c];
        if (resid_nchw) v += resid_nchw[((size_t)(b * Cc + c)) * HW + p];
        out_h[((size_t)b * HW + p) * Cc + c] = (half_t)v;
        if (out_f) out_f[((size_t)b * HW + p) * Cc + c] = v;
    }
}

// ---------------- offset |.| mean ----------------
__global__ void abs_sum_kernel(const float* __restrict__ om, int B, int Ctot, int HW,
                               float* __restrict__ acc)
{
    long long total = (long long)B * 18 * HW;
    float s = 0.f;
    for (long long i = (long long)blockIdx.x * blockDim.x + threadIdx.x; i < total;
         i += (long long)gridDim.x * blockDim.x) {
        int pos = (int)(i % HW);
        int c   = (int)((i / HW) % 18);
        int b   = (int)(i / ((long long)18 * HW));
        s += fabsf(om[((size_t)(b * Ctot + c)) * HW + pos]);
    }
#pragma unroll
    for (int off = 32; off > 0; off >>= 1) s += __shfl_down(s, off);
    __shared__ float ws_[4];
    int lane = threadIdx.x & 63, w = threadIdx.x >> 6;
    if (lane == 0) ws_[w] = s;
    __syncthreads();
    if (threadIdx.x == 0) {
        float t = 0.f;
        int nw = blockDim.x >> 6;
        for (int i = 0; i < nw; ++i) t += ws_[i];
        atomicAdd(acc, t);
    }
}

__global__ void zero2_kernel(float* a) { if (threadIdx.x < 2) a[threadIdx.x] = 0.f; }

__global__ void finalize_kernel(const float* __restrict__ acc, float* __restrict__ out) {
    out[0] = 0.5f * (acc[0] / (4.f * 18.f * 128.f * 128.f)
                   + acc[1] / (4.f * 18.f * 64.f * 64.f));
}

extern "C" void kernel_launch(void* const* d_in, const int* in_sizes, int n_in,
                              void* d_out, int out_size, void* d_ws, size_t ws_size,
                              hipStream_t stream)
{
    const float* x      = (const float*)d_in[0];
    const float* skip1  = (const float*)d_in[1];
    const float* skip2  = (const float*)d_in[2];
    const float* res_w  = (const float*)d_in[3];
    const float* res_b  = (const float*)d_in[4];
    const float* w1     = (const float*)d_in[5];
    const float* b1     = (const float*)d_in[6];
    const float* w2     = (const float*)d_in[7];
    const float* b2     = (const float*)d_in[8];
    const float* w3     = (const float*)d_in[9];
    const float* b3     = (const float*)d_in[10];
    const float* off2_w = (const float*)d_in[11];
    const float* off2_b = (const float*)d_in[12];
    const float* dcn2_w = (const float*)d_in[13];
    const float* dcn2_b = (const float*)d_in[14];
    const float* off1_w = (const float*)d_in[15];
    const float* off1_b = (const float*)d_in[16];
    const float* dcn1_w = (const float*)d_in[17];
    const float* dcn1_b = (const float*)d_in[18];

    char* base = (char*)d_ws;
    size_t o = 0;
    auto alloc = [&](size_t bytes) { size_t r = o; o += (bytes + 15) & ~(size_t)15; return r; };
    half_t* x_h   = (half_t*)(base + alloc(1048576ull * 2));
    half_t* s1c   = (half_t*)(base + alloc(4194304ull * 2));
    half_t* s2c   = (half_t*)(base + alloc(2097152ull * 2));
    float*  scrf  = (float*)(base + alloc(1048576ull * 4));  // res conv out (fp32 NHWC)
    half_t* tB_h  = (half_t*)(base + alloc(1048576ull * 2));
    float*  cur_f = (float*)(base + alloc(1048576ull * 4));
    half_t* cur_h = (half_t*)(base + alloc(1048576ull * 2));
    half_t* out1h = (half_t*)(base + alloc(2097152ull * 2));
    half_t* pre2h = (half_t*)(base + alloc(2097152ull * 2));
    half_t* out2h = (half_t*)(base + alloc(4194304ull * 2));
    half_t* pre1h = (half_t*)(base + alloc(4194304ull * 2));
    float*  om2f  = (float*)(base + alloc(442368ull * 4));
    float*  om1f  = (float*)(base + alloc(1769472ull * 4));
    half_t* wres  = (half_t*)(base + alloc(4ull * 589824 * 2));
    half_t* w1t   = (half_t*)(base + alloc(819200ull * 2));
    half_t* w2t   = (half_t*)(base + alloc(409600ull * 2));
    half_t* off2t = (half_t*)(base + alloc(73728ull * 2));
    half_t* off1t = (half_t*)(base + alloc(36864ull * 2));
    half_t* w3t   = (half_t*)(base + alloc(100352ull * 2));
    half_t* dcn2t = (half_t*)(base + alloc(147456ull * 2));
    half_t* dcn1t = (half_t*)(base + alloc(36864ull * 2));
    float*  part  = (float*)(base + alloc(16384ull * 4));
    float*  acc   = (float*)(base + alloc(16));
    if (ws_size < o) return;

    float* outp = (float*)d_out;

    zero2_kernel<<<dim3(1), dim3(64), 0, stream>>>(acc);

    // ---- converts ----
    cvt_nchw_nhwc<<<dim3(4096), 256, 0, stream>>>(x, x_h, 256, 32, 32, 1048576);
    cvt_nchw_nhwc<<<dim3(16384), 256, 0, stream>>>(skip1, s1c, 64, 128, 128, 4194304);
    cvt_nchw_nhwc<<<dim3(8192), 256, 0, stream>>>(skip2, s2c, 128, 64, 64, 2097152);

    // ---- weight transforms ----
    for (int j = 0; j < 4; ++j)
        wtrans_conv<<<dim3(2304), 256, 0, stream>>>(res_w + (size_t)j * 589824,
                                                    wres + (size_t)j * 589824, 256, 256, 256, 9);
    wtrans_conv<<<dim3(3200), 256, 0, stream>>>(w1, w1t, 128, 128, 256, 25);
    wtrans_conv<<<dim3(1600), 256, 0, stream>>>(w2, w2t, 64, 64, 256, 25);
    wtrans_conv<<<dim3(288), 256, 0, stream>>>(off2_w, off2t, 27, 32, 256, 9);
    wtrans_conv<<<dim3(144), 256, 0, stream>>>(off1_w, off1t, 27, 32, 128, 9);
    wtrans_conv<<<dim3(392), 256, 0, stream>>>(w3, w3t, 3, 16, 128, 49);
    wtrans_dcn<<<dim3(576), 256, 0, stream>>>(dcn2_w, dcn2t, 128, 128);
    wtrans_dcn<<<dim3(144), 256, 0, stream>>>(dcn1_w, dcn1t, 64, 64);

    // ---- residual blocks (256ch @32x32), fp32 conv-out + fp32 residual carry ----
    for (int i = 0; i < 2; ++i) {
        const half_t* in_h = (i == 0) ? x_h : cur_h;
        mfma_conv<3, 0, 1, 32><<<dim3(64, 8), 256, 0, stream>>>(
            in_h, nullptr, 256, 0, wres + (size_t)(i * 2) * 589824, res_b + (i * 2) * 256,
            scrf, 256, 256, 32, 32, 0, 2);
        inorm_p1<float><<<dim3(32), 256, 0, stream>>>(scrf, part, 256, 1024, 8);
        inorm_p2<float><<<dim3(32), 256, 0, stream>>>(scrf, tB_h, nullptr, nullptr, nullptr,
                                                      part, 256, 1024, 8, 1);
        mfma_conv<3, 0, 1, 32><<<dim3(64, 8), 256, 0, stream>>>(
            tB_h, nullptr, 256, 0, wres + (size_t)(i * 2 + 1) * 589824, res_b + (i * 2 + 1) * 256,
            scrf, 256, 256, 32, 32, 0, 2);
        inorm_p1<float><<<dim3(32), 256, 0, stream>>>(scrf, part, 256, 1024, 8);
        inorm_p2<float><<<dim3(32), 256, 0, stream>>>(scrf, cur_h, cur_f,
                                                      (i == 0) ? nullptr : cur_f,
                                                      (i == 0) ? x : nullptr,
                                                      part, 256, 1024, 8, 0);
    }

    // ---- conv1: up2+refpad2+5x5 (256->128) @64x64, IN+relu ----
    mfma_conv<5, 1, 1, 32><<<dim3(256, 4), 256, 0, stream>>>(
        cur_h, nullptr, 256, 0, w1t, b1, out1h, 128, 128, 64, 64, 0, 0);
    inorm_p1<half_t><<<dim3(32), 256, 0, stream>>>(out1h, part, 128, 4096, 8);
    inorm_p2<half_t><<<dim3(32), 256, 0, stream>>>(out1h, out1h, nullptr, nullptr, nullptr,
                                                   part, 128, 4096, 8, 1);

    // ---- om2 = 3x3 zero-pad conv on concat[out1, s2c] -> 27ch fp32 NCHW ----
    mfma_conv<3, 0, 0, 32><<<dim3(256, 1), 256, 0, stream>>>(
        out1h, s2c, 128, 128, off2t, off2_b, om2f, 27, 32, 64, 64, 0, 1);

    // ---- pre2 = deform_conv(skip2, om2) ----
    mfma_dcn<128><<<dim3(256, 4), 256, 0, stream>>>(s2c, om2f, dcn2t, dcn2_b, pre2h, 128, 64, 64);

    // ---- conv2: up2+refpad2+5x5 concat[pre2,out1] (256->64) @128x128, IN+relu ----
    mfma_conv<5, 1, 1, 32><<<dim3(1024, 2), 256, 0, stream>>>(
        pre2h, out1h, 128, 128, w2t, b2, out2h, 64, 64, 128, 128, 0, 0);
    inorm_p1<half_t><<<dim3(32), 256, 0, stream>>>(out2h, part, 64, 16384, 8);
    inorm_p2<half_t><<<dim3(32), 256, 0, stream>>>(out2h, out2h, nullptr, nullptr, nullptr,
                                                   part, 64, 16384, 8, 1);

    // ---- om1 = 3x3 zero-pad conv on concat[out2, s1c] -> 27ch fp32 NCHW ----
    mfma_conv<3, 0, 0, 32><<<dim3(1024, 1), 256, 0, stream>>>(
        out2h, s1c, 64, 64, off1t, off1_b, om1f, 27, 32, 128, 128, 0, 1);

    // ---- pre1 = deform_conv(skip1, om1) ----
    mfma_dcn<64><<<dim3(1024, 2), 256, 0, stream>>>(s1c, om1f, dcn1t, dcn1_b, pre1h, 64, 128, 128);

    // ---- final: 7x7 refpad3 concat[pre1,out2] -> 3ch fp32 NCHW + tanh ----
    mfma_conv<7, 0, 1, 16><<<dim3(1024, 1), 256, 0, stream>>>(
        pre1h, out2h, 64, 64, w3t, b3, outp, 3, 16, 128, 128, 1, 1);

    // ---- offset_sum ----
    abs_sum_kernel<<<dim3(256), 256, 0, stream>>>(om1f, 4, 27, 16384, acc + 0);
    abs_sum_kernel<<<dim3(256), 256, 0, stream>>>(om2f, 4, 27, 4096, acc + 1);
    finalize_kernel<<<dim3(1), dim3(1), 0, stream>>>(acc, outp + 196608);
}

// Round 6
// 1323.836 us; speedup vs baseline: 14.4773x; 1.1082x over previous
//
#include <hip/hip_runtime.h>
#include <cmath>

#define EPS 1e-5f

typedef _Float16 half_t;
typedef __attribute__((ext_vector_type(8))) _Float16 half8;
typedef __attribute__((ext_vector_type(8))) short short8;
typedef __attribute__((ext_vector_type(4))) float f32x4;

__device__ __forceinline__ int reflect_idx(int p, int S) {
    if (p < 0) p = -p;
    if (p >= S) p = 2 * S - 2 - p;
    return p;
}
__device__ __forceinline__ float hlo(unsigned v) {
    return (float)__builtin_bit_cast(half_t, (unsigned short)(v & 0xffffu));
}
__device__ __forceinline__ float hhi(unsigned v) {
    return (float)__builtin_bit_cast(half_t, (unsigned short)(v >> 16));
}
__device__ __forceinline__ unsigned short hbits(float f) {
    return __builtin_bit_cast(unsigned short, (half_t)f);
}

// ---------------- weight transforms (fp32 -> fp16) ----------------
// conv weights [Co][Cin][KK] -> [cb][kk][Cop][32] where c = cb*32 + cl.
// Per-K-chunk weights contiguous -> L2-friendly streaming in the main loop.
__global__ void wtrans_conv(const float* __restrict__ w, half_t* __restrict__ wt,
                            int Co, int Cop, int Cin, int KK)
{
    int i = blockIdx.x * 256 + threadIdx.x;
    int total = KK * Cop * Cin;
    if (i >= total) return;
    int cl = i & 31;
    int oc = (i >> 5) % Cop;
    int rest = (i >> 5) / Cop;     // cb*KK + kk
    int kk = rest % KK;
    int cb = rest / KK;
    int c = (cb << 5) + cl;
    float v = (oc < Co) ? w[((size_t)oc * Cin + c) * KK + kk] : 0.f;
    wt[i] = (half_t)v;
}

// dcn weights [Co][Cin][9] -> [cb][Co][32] with kidx = k*Cin + c = cb*32 + cl
__global__ void wtrans_dcn(const float* __restrict__ w, half_t* __restrict__ wt,
                           int Co, int Cin)
{
    int i = blockIdx.x * 256 + threadIdx.x;
    int total = Co * 9 * Cin;
    if (i >= total) return;
    int cl = i & 31;
    int oc = (i >> 5) % Co;
    int cb = (i >> 5) / Co;
    int kidx = (cb << 5) + cl;
    int k = kidx / Cin, c = kidx % Cin;
    wt[i] = (half_t)w[((size_t)oc * Cin + c) * 9 + k];
}

// ---------------- NCHW fp32 -> NHWC fp16 ----------------
__global__ void cvt_nchw_nhwc(const float* __restrict__ in, half_t* __restrict__ out,
                              int C, int H, int W, int total)
{
    int i = blockIdx.x * 256 + threadIdx.x;
    if (i >= total) return;
    int c = i % C;
    int x = (i / C) % W;
    int y = (i / (C * W)) % H;
    int b = i / (C * W * H);
    out[i] = (half_t)in[(((size_t)b * C + c) * H + y) * W + x];
}

// ---------------- MFMA implicit-GEMM conv ----------------
// Output tile 8x8 positions x COB ocs per block. 4 waves, double-buffered LDS,
// bank-optimal 64B rows with chunk-XOR swizzle.
// Input NHWC fp16 = concat(in1[C1], in2[C2]). wt: [cb][kk][Cop][32] fp16.
// outfmt: 0 = fp16 NHWC (stride Co), 1 = fp32 NCHW, 2 = fp32 NHWC. act 1 = tanh.
template<int K, int UP, int REFLECT, int COB>
__global__ __launch_bounds__(256, 4)
void mfma_conv(const half_t* __restrict__ in1, const half_t* __restrict__ in2,
               int C1, int C2,
               const half_t* __restrict__ wt, const float* __restrict__ bias,
               void* __restrict__ outp,
               int Co, int Cop, int Hout, int Wout, int act, int outfmt)
{
    constexpr int TH = 8, TW = 8, PAD = K / 2;
    constexpr int PR = TH + K - 1, PW = TW + K - 1;
    constexpr int NPOS = PR * PW, KK = K * K;
    constexpr int NM = COB / 16;
    constexpr int NNW = NM;
    constexpr int LDSB = NPOS * 64;            // bytes per buffer
    constexpr int NELEM = NPOS * 4;            // 16B chunks per buffer
    constexpr int NE = (NELEM + 255) / 256;    // chunks per thread

    __shared__ __align__(16) char lds[2 * LDSB];

    const int Cin = C1 + C2;
    const int Hin = UP ? (Hout >> 1) : Hout;
    const int Win = UP ? (Wout >> 1) : Wout;
    const int NTX = Wout / TW, NTY = Hout / TH;

    const int tid = threadIdx.x;
    const int wv = tid >> 6, lane = tid & 63, l15 = lane & 15, kg = lane >> 4;
    const int bx = blockIdx.x;
    const int xt = (bx % NTX) * TW;
    const int yt = ((bx / NTX) % NTY) * TH;
    const int b  = bx / (NTX * NTY);
    const int ocb = blockIdx.y * COB;
    const int m  = wv % NM;
    const int n0 = (wv / NM) * NM;

    f32x4 acc[NNW];
#pragma unroll
    for (int t = 0; t < NNW; ++t) acc[t] = (f32x4){0.f, 0.f, 0.f, 0.f};

    int ipos[NNW];
#pragma unroll
    for (int t = 0; t < NNW; ++t) {
        int pos = (n0 + t) * 16 + l15;
        ipos[t] = (pos >> 3) * PW + (pos & 7);
    }

    // ---- precompute staging element spatial indices (constant across chunks) ----
    int esi[NE]; bool eok[NE];
#pragma unroll
    for (int i = 0; i < NE; ++i) {
        int e = tid + i * 256;
        if (e < NELEM) {
            int p = e >> 2;
            int py = p / PW, px = p % PW;
            int ly = yt + py - PAD, lx = xt + px - PAD;
            bool ok = true;
            if (REFLECT) { ly = reflect_idx(ly, Hout); lx = reflect_idx(lx, Wout); }
            else {
                ok = (ly >= 0) && (ly < Hout) && (lx >= 0) && (lx < Wout);
                if (!ok) { ly = 0; lx = 0; }
            }
            int sy = UP ? (ly >> 1) : ly;
            int sx = UP ? (lx >> 1) : lx;
            esi[i] = (b * Hin + sy) * Win + sx;
            eok[i] = ok;
        }
    }

    short8 streg[NE];
    auto load_chunk = [&](int cb) {
#pragma unroll
        for (int i = 0; i < NE; ++i) {
            int e = tid + i * 256;
            if (e < NELEM) {
                int g = e & 3;
                int gc = (cb << 5) + g * 8;
                const half_t* src; int Cl, c;
                if (gc < C1) { src = in1; Cl = C1; c = gc; }
                else         { src = in2; Cl = C2; c = gc - C1; }
                streg[i] = eok[i] ? *(const short8*)(src + (size_t)esi[i] * Cl + c)
                                  : (short8)0;
            }
        }
    };
    auto write_lds = [&](int buf) {
#pragma unroll
        for (int i = 0; i < NE; ++i) {
            int e = tid + i * 256;
            if (e < NELEM) {
                int p = e >> 2, g = e & 3;
                *(short8*)(lds + buf * LDSB + p * 64 + ((g ^ (p & 3)) << 4)) = streg[i];
            }
        }
    };

    const int NCB = Cin >> 5;
    const half_t* wbase = wt + (size_t)(ocb + m * 16 + l15) * 32 + (kg << 3);

    // ---- prologue ----
    load_chunk(0);
    write_lds(0);
    int cur = 0;
    for (int cb = 0; cb < NCB; ++cb) {
        if (cb + 1 < NCB) load_chunk(cb + 1);   // issue next-chunk global loads
        __syncthreads();                        // buf[cur] ready
        // ---- compute on buf[cur] ----
        const half_t* wc = wbase + (size_t)cb * KK * Cop * 32;
        const char* lb = lds + cur * LDSB;
#pragma unroll
        for (int kk = 0; kk < KK; ++kk) {
            half8 a = *(const half8*)(wc + (size_t)kk * Cop * 32);
            int ikk = (kk / K) * PW + (kk % K);
#pragma unroll
            for (int t = 0; t < NNW; ++t) {
                int idx = ipos[t] + ikk;
                half8 bb = *(const half8*)(lb + idx * 64 + ((kg ^ (idx & 3)) << 4));
                acc[t] = __builtin_amdgcn_mfma_f32_16x16x32_f16(a, bb, acc[t], 0, 0, 0);
            }
        }
        if (cb + 1 < NCB) write_lds(cur ^ 1);   // safe: other buf last read pre-barrier
        cur ^= 1;
    }

    // ---- epilogue ----
#pragma unroll
    for (int t = 0; t < NNW; ++t) {
        int pos = (n0 + t) * 16 + l15;
        int y = yt + (pos >> 3), x = xt + (pos & 7);
#pragma unroll
        for (int j = 0; j < 4; ++j) {
            int oc = ocb + m * 16 + kg * 4 + j;
            if (oc < Co) {
                float v = acc[t][j] + bias[oc];
                if (act) v = tanhf(v);
                if (outfmt == 0)
                    ((half_t*)outp)[((size_t)(b * Hout + y) * Wout + x) * Co + oc] = (half_t)v;
                else if (outfmt == 1)
                    ((float*)outp)[(((size_t)b * Co + oc) * Hout + y) * Wout + x] = v;
                else
                    ((float*)outp)[((size_t)(b * Hout + y) * Wout + x) * Co + oc] = v;
            }
        }
    }
}

// ---------------- MFMA deformable conv (gather fused into staging) ----------------
// xs: skip NHWC fp16 [B][H][W][C]; om: fp32 NCHW [B][27][H][W];
// wtd: [cb][Co][32] fp16 (kidx = k*C+c = cb*32+cl); out fp16 NHWC stride Co.
template<int C>
__global__ __launch_bounds__(256, 4)
void mfma_dcn(const half_t* __restrict__ xs, const float* __restrict__ om,
              const half_t* __restrict__ wtd, const float* __restrict__ bias,
              half_t* __restrict__ outb, int Co, int H, int W)
{
    __shared__ __align__(16) char lds[64 * 64];
    __shared__ int   sy0[64], sx0[64];
    __shared__ float sdy[64], sdx[64], smk[64];

    const int NTX = W / 8, NTY = H / 8;
    const int tid = threadIdx.x;
    const int wv = tid >> 6, lane = tid & 63, l15 = lane & 15, kg = lane >> 4;
    const int bx = blockIdx.x;
    const int xt = (bx % NTX) * 8;
    const int yt = ((bx / NTX) % NTY) * 8;
    const int b  = bx / (NTX * NTY);
    const int ocb = blockIdx.y * 32;
    const int m = wv & 1, n0 = (wv >> 1) * 2;
    const int HW = H * W;

    f32x4 acc[2];
    acc[0] = (f32x4){0.f, 0.f, 0.f, 0.f};
    acc[1] = (f32x4){0.f, 0.f, 0.f, 0.f};
    int boff[2];
#pragma unroll
    for (int t = 0; t < 2; ++t) {
        int pos = (n0 + t) * 16 + l15;
        boff[t] = pos * 64 + ((kg ^ (pos & 3)) << 4);
    }

    const half_t* wlane = wtd + (size_t)(ocb + m * 16 + l15) * 32 + (kg << 3);

    const int NCB = (9 * C) >> 5;
    for (int cb = 0; cb < NCB; ++cb) {
        const int kidx0 = cb << 5;
        const int k = kidx0 / C, c0 = kidx0 % C;
        if (c0 == 0) {
            __syncthreads();       // all waves past previous gather/mfma
            if (tid < 64) {
                int pos = tid;
                int y = yt + (pos >> 3), x = xt + (pos & 7);
                size_t obase = (size_t)b * 27 * HW + (size_t)y * W + x;
                float offy = om[obase + (size_t)(2 * k) * HW];
                float offx = om[obase + (size_t)(2 * k + 1) * HW];
                float ml   = om[obase + (size_t)(18 + k) * HW];
                float mk = 1.f / (1.f + expf(-ml));
                float py = (float)(y - 1 + k / 3) + offy;
                float px = (float)(x - 1 + k % 3) + offx;
                float fy = floorf(py), fx = floorf(px);
                sy0[pos] = (int)fy; sx0[pos] = (int)fx;
                sdy[pos] = py - fy; sdx[pos] = px - fx; smk[pos] = mk;
            }
        }
        __syncthreads();           // tables ready; lds free (prev mfma done)
        for (int u = tid; u < 1024; u += 256) {
            int pos = u >> 4, cp = u & 15;
            int c = c0 + cp * 2;
            int y0 = sy0[pos], x0 = sx0[pos];
            float dy = sdy[pos], dx = sdx[pos], mk = smk[pos];
            int y1 = y0 + 1, x1 = x0 + 1;
            float w00 = (1.f - dy) * (1.f - dx) * mk;
            float w01 = (1.f - dy) * dx * mk;
            float w10 = dy * (1.f - dx) * mk;
            float w11 = dy * dx * mk;
            bool vy0 = (y0 >= 0) && (y0 < H), vy1 = (y1 >= 0) && (y1 < H);
            bool vx0 = (x0 >= 0) && (x0 < W), vx1 = (x1 >= 0) && (x1 < W);
            if (!(vy0 && vx0)) w00 = 0.f;
            if (!(vy0 && vx1)) w01 = 0.f;
            if (!(vy1 && vx0)) w10 = 0.f;
            if (!(vy1 && vx1)) w11 = 0.f;
            int yc0 = min(max(y0, 0), H - 1), yc1 = min(max(y1, 0), H - 1);
            int xc0 = min(max(x0, 0), W - 1), xc1 = min(max(x1, 0), W - 1);
            const half_t* xb = xs + c;
            unsigned v00 = *(const unsigned*)(xb + ((size_t)(b * H + yc0) * W + xc0) * C);
            unsigned v01 = *(const unsigned*)(xb + ((size_t)(b * H + yc0) * W + xc1) * C);
            unsigned v10 = *(const unsigned*)(xb + ((size_t)(b * H + yc1) * W + xc0) * C);
            unsigned v11 = *(const unsigned*)(xb + ((size_t)(b * H + yc1) * W + xc1) * C);
            float lo = hlo(v00) * w00 + hlo(v01) * w01 + hlo(v10) * w10 + hlo(v11) * w11;
            float hi = hhi(v00) * w00 + hhi(v01) * w01 + hhi(v10) * w10 + hhi(v11) * w11;
            unsigned r = (unsigned)hbits(lo) | ((unsigned)hbits(hi) << 16);
            *(unsigned*)(lds + pos * 64 + ((((cp >> 2) ^ (pos & 3)) << 4) | ((cp & 3) << 2))) = r;
        }
        __syncthreads();
        half8 a = *(const half8*)(wlane + (size_t)cb * Co * 32);
#pragma unroll
        for (int t = 0; t < 2; ++t) {
            half8 bb = *(const half8*)(lds + boff[t]);
            acc[t] = __builtin_amdgcn_mfma_f32_16x16x32_f16(a, bb, acc[t], 0, 0, 0);
        }
    }

#pragma unroll
    for (int t = 0; t < 2; ++t) {
        int pos = (n0 + t) * 16 + l15;
        int y = yt + (pos >> 3), x = xt + (pos & 7);
#pragma unroll
        for (int j = 0; j < 4; ++j) {
            int oc = ocb + m * 16 + kg * 4 + j;
            float v = acc[t][j] + bias[oc];
            outb[((size_t)(b * H + y) * W + x) * Co + oc] = (half_t)v;
        }
    }
}

// ---------------- InstanceNorm (NHWC), 2 passes, templated input dtype ----------------
template<typename TI>
__global__ void inorm_p1(const TI* __restrict__ in, float* __restrict__ part,
                         int Cc, int HW, int NS)
{
    int bs = blockIdx.x; int s = bs % NS; int b = bs / NS;
    int tid = threadIdx.x;
    int c = tid % Cc, r = tid / Cc, G = 256 / Cc;
    int rows = HW / NS, p0 = s * rows;
    const TI* base = in + (size_t)b * HW * Cc;
    float sm = 0.f, sq = 0.f;
    for (int p = p0 + r; p < p0 + rows; p += G) {
        float v = (float)base[(size_t)p * Cc + c];
        sm += v; sq += v * v;
    }
    __shared__ float l1[256], l2[256];
    l1[tid] = sm; l2[tid] = sq;
    __syncthreads();
    if (r == 0) {
        for (int g = 1; g < G; ++g) { sm += l1[g * Cc + c]; sq += l2[g * Cc + c]; }
        part[((size_t)(b * NS + s) * Cc + c) * 2]     = sm;
        part[((size_t)(b * NS + s) * Cc + c) * 2 + 1] = sq;
    }
}

template<typename TI>
__global__ void inorm_p2(const TI* __restrict__ in, half_t* __restrict__ out_h,
                         float* __restrict__ out_f,
                         const float* __restrict__ resid_nhwc,
                         const float* __restrict__ resid_nchw,
                         const float* __restrict__ part,
                         int Cc, int HW, int NS, int relu)
{
    int bs = blockIdx.x; int s = bs % NS; int b = bs / NS;
    int tid = threadIdx.x;
    int c = tid % Cc, r = tid / Cc, G = 256 / Cc;
    float S = 0.f, Q = 0.f;
    for (int s2 = 0; s2 < NS; ++s2) {
        S += part[((size_t)(b * NS + s2) * Cc + c) * 2];
        Q += part[((size_t)(b * NS + s2) * Cc + c) * 2 + 1];
    }
    float mmean = S / HW;
    float var = Q / HW - mmean * mmean;
    if (var < 0.f) var = 0.f;
    float rs = rsqrtf(var + EPS);
    int rows = HW / NS, p0 = s * rows;
    const TI* bi = in + (size_t)b * HW * Cc;
    for (int p = p0 + r; p < p0 + rows; p += G) {
        float v = ((float)bi[(size_t)p * Cc + c] - mmean) * rs;
        if (relu) v = fmaxf(v, 0.f);
        if (resid_nhwc) v += resid_nhwc[((size_t)b * HW + p) * Cc + c];
        if (resid_nchw) v += resid_nchw[((size_t)(b * Cc + c)) * HW + p];
        out_h[((size_t)b * HW + p) * Cc + c] = (half_t)v;
        if (out_f) out_f[((size_t)b * HW + p) * Cc + c] = v;
    }
}

// ---------------- offset |.| mean ----------------
__global__ void abs_sum_kernel(const float* __restrict__ om, int B, int Ctot, int HW,
                               float* __restrict__ acc)
{
    long long total = (long long)B * 18 * HW;
    float s = 0.f;
    for (long long i = (long long)blockIdx.x * blockDim.x + threadIdx.x; i < total;
         i += (long long)gridDim.x * blockDim.x) {
        int pos = (int)(i % HW);
        int c   = (int)((i / HW) % 18);
        int b   = (int)(i / ((long long)18 * HW));
        s += fabsf(om[((size_t)(b * Ctot + c)) * HW + pos]);
    }
#pragma unroll
    for (int off = 32; off > 0; off >>= 1) s += __shfl_down(s, off);
    __shared__ float ws_[4];
    int lane = threadIdx.x & 63, w = threadIdx.x >> 6;
    if (lane == 0) ws_[w] = s;
    __syncthreads();
    if (threadIdx.x == 0) {
        float t = 0.f;
        int nw = blockDim.x >> 6;
        for (int i = 0; i < nw; ++i) t += ws_[i];
        atomicAdd(acc, t);
    }
}

__global__ void zero2_kernel(float* a) { if (threadIdx.x < 2) a[threadIdx.x] = 0.f; }

__global__ void finalize_kernel(const float* __restrict__ acc, float* __restrict__ out) {
    out[0] = 0.5f * (acc[0] / (4.f * 18.f * 128.f * 128.f)
                   + acc[1] / (4.f * 18.f * 64.f * 64.f));
}

extern "C" void kernel_launch(void* const* d_in, const int* in_sizes, int n_in,
                              void* d_out, int out_size, void* d_ws, size_t ws_size,
                              hipStream_t stream)
{
    const float* x      = (const float*)d_in[0];
    const float* skip1  = (const float*)d_in[1];
    const float* skip2  = (const float*)d_in[2];
    const float* res_w  = (const float*)d_in[3];
    const float* res_b  = (const float*)d_in[4];
    const float* w1     = (const float*)d_in[5];
    const float* b1     = (const float*)d_in[6];
    const float* w2     = (const float*)d_in[7];
    const float* b2     = (const float*)d_in[8];
    const float* w3     = (const float*)d_in[9];
    const float* b3     = (const float*)d_in[10];
    const float* off2_w = (const float*)d_in[11];
    const float* off2_b = (const float*)d_in[12];
    const float* dcn2_w = (const float*)d_in[13];
    const float* dcn2_b = (const float*)d_in[14];
    const float* off1_w = (const float*)d_in[15];
    const float* off1_b = (const float*)d_in[16];
    const float* dcn1_w = (const float*)d_in[17];
    const float* dcn1_b = (const float*)d_in[18];

    char* base = (char*)d_ws;
    size_t o = 0;
    auto alloc = [&](size_t bytes) { size_t r = o; o += (bytes + 15) & ~(size_t)15; return r; };
    half_t* x_h   = (half_t*)(base + alloc(1048576ull * 2));
    half_t* s1c   = (half_t*)(base + alloc(4194304ull * 2));
    half_t* s2c   = (half_t*)(base + alloc(2097152ull * 2));
    float*  scrf  = (float*)(base + alloc(1048576ull * 4));
    half_t* tB_h  = (half_t*)(base + alloc(1048576ull * 2));
    float*  cur_f = (float*)(base + alloc(1048576ull * 4));
    half_t* cur_h = (half_t*)(base + alloc(1048576ull * 2));
    half_t* out1h = (half_t*)(base + alloc(2097152ull * 2));
    half_t* pre2h = (half_t*)(base + alloc(2097152ull * 2));
    half_t* out2h = (half_t*)(base + alloc(4194304ull * 2));
    half_t* pre1h = (half_t*)(base + alloc(4194304ull * 2));
    float*  om2f  = (float*)(base + alloc(442368ull * 4));
    float*  om1f  = (float*)(base + alloc(1769472ull * 4));
    half_t* wres  = (half_t*)(base + alloc(4ull * 589824 * 2));
    half_t* w1t   = (half_t*)(base + alloc(819200ull * 2));
    half_t* w2t   = (half_t*)(base + alloc(409600ull * 2));
    half_t* off2t = (half_t*)(base + alloc(73728ull * 2));
    half_t* off1t = (half_t*)(base + alloc(36864ull * 2));
    half_t* w3t   = (half_t*)(base + alloc(100352ull * 2));
    half_t* dcn2t = (half_t*)(base + alloc(147456ull * 2));
    half_t* dcn1t = (half_t*)(base + alloc(36864ull * 2));
    float*  part  = (float*)(base + alloc(16384ull * 4));
    float*  acc   = (float*)(base + alloc(16));
    if (ws_size < o) return;

    float* outp = (float*)d_out;

    zero2_kernel<<<dim3(1), dim3(64), 0, stream>>>(acc);

    // ---- converts ----
    cvt_nchw_nhwc<<<dim3(4096), 256, 0, stream>>>(x, x_h, 256, 32, 32, 1048576);
    cvt_nchw_nhwc<<<dim3(16384), 256, 0, stream>>>(skip1, s1c, 64, 128, 128, 4194304);
    cvt_nchw_nhwc<<<dim3(8192), 256, 0, stream>>>(skip2, s2c, 128, 64, 64, 2097152);

    // ---- weight transforms ----
    for (int j = 0; j < 4; ++j)
        wtrans_conv<<<dim3(2304), 256, 0, stream>>>(res_w + (size_t)j * 589824,
                                                    wres + (size_t)j * 589824, 256, 256, 256, 9);
    wtrans_conv<<<dim3(3200), 256, 0, stream>>>(w1, w1t, 128, 128, 256, 25);
    wtrans_conv<<<dim3(1600), 256, 0, stream>>>(w2, w2t, 64, 64, 256, 25);
    wtrans_conv<<<dim3(288), 256, 0, stream>>>(off2_w, off2t, 27, 32, 256, 9);
    wtrans_conv<<<dim3(144), 256, 0, stream>>>(off1_w, off1t, 27, 32, 128, 9);
    wtrans_conv<<<dim3(392), 256, 0, stream>>>(w3, w3t, 3, 16, 128, 49);
    wtrans_dcn<<<dim3(576), 256, 0, stream>>>(dcn2_w, dcn2t, 128, 128);
    wtrans_dcn<<<dim3(144), 256, 0, stream>>>(dcn1_w, dcn1t, 64, 64);

    // ---- residual blocks (256ch @32x32), fp32 conv-out + fp32 residual carry ----
    for (int i = 0; i < 2; ++i) {
        const half_t* in_h = (i == 0) ? x_h : cur_h;
        mfma_conv<3, 0, 1, 32><<<dim3(64, 8), 256, 0, stream>>>(
            in_h, nullptr, 256, 0, wres + (size_t)(i * 2) * 589824, res_b + (i * 2) * 256,
            scrf, 256, 256, 32, 32, 0, 2);
        inorm_p1<float><<<dim3(32), 256, 0, stream>>>(scrf, part, 256, 1024, 8);
        inorm_p2<float><<<dim3(32), 256, 0, stream>>>(scrf, tB_h, nullptr, nullptr, nullptr,
                                                      part, 256, 1024, 8, 1);
        mfma_conv<3, 0, 1, 32><<<dim3(64, 8), 256, 0, stream>>>(
            tB_h, nullptr, 256, 0, wres + (size_t)(i * 2 + 1) * 589824, res_b + (i * 2 + 1) * 256,
            scrf, 256, 256, 32, 32, 0, 2);
        inorm_p1<float><<<dim3(32), 256, 0, stream>>>(scrf, part, 256, 1024, 8);
        inorm_p2<float><<<dim3(32), 256, 0, stream>>>(scrf, cur_h, cur_f,
                                                      (i == 0) ? nullptr : cur_f,
                                                      (i == 0) ? x : nullptr,
                                                      part, 256, 1024, 8, 0);
    }

    // ---- conv1: up2+refpad2+5x5 (256->128) @64x64, IN+relu ----
    mfma_conv<5, 1, 1, 32><<<dim3(256, 4), 256, 0, stream>>>(
        cur_h, nullptr, 256, 0, w1t, b1, out1h, 128, 128, 64, 64, 0, 0);
    inorm_p1<half_t><<<dim3(32), 256, 0, stream>>>(out1h, part, 128, 4096, 8);
    inorm_p2<half_t><<<dim3(32), 256, 0, stream>>>(out1h, out1h, nullptr, nullptr, nullptr,
                                                   part, 128, 4096, 8, 1);

    // ---- om2 = 3x3 zero-pad conv on concat[out1, s2c] -> 27ch fp32 NCHW ----
    mfma_conv<3, 0, 0, 32><<<dim3(256, 1), 256, 0, stream>>>(
        out1h, s2c, 128, 128, off2t, off2_b, om2f, 27, 32, 64, 64, 0, 1);

    // ---- pre2 = deform_conv(skip2, om2) ----
    mfma_dcn<128><<<dim3(256, 4), 256, 0, stream>>>(s2c, om2f, dcn2t, dcn2_b, pre2h, 128, 64, 64);

    // ---- conv2: up2+refpad2+5x5 concat[pre2,out1] (256->64) @128x128, IN+relu ----
    mfma_conv<5, 1, 1, 32><<<dim3(1024, 2), 256, 0, stream>>>(
        pre2h, out1h, 128, 128, w2t, b2, out2h, 64, 64, 128, 128, 0, 0);
    inorm_p1<half_t><<<dim3(32), 256, 0, stream>>>(out2h, part, 64, 16384, 8);
    inorm_p2<half_t><<<dim3(32), 256, 0, stream>>>(out2h, out2h, nullptr, nullptr, nullptr,
                                                   part, 64, 16384, 8, 1);

    // ---- om1 = 3x3 zero-pad conv on concat[out2, s1c] -> 27ch fp32 NCHW ----
    mfma_conv<3, 0, 0, 32><<<dim3(1024, 1), 256, 0, stream>>>(
        out2h, s1c, 64, 64, off1t, off1_b, om1f, 27, 32, 128, 128, 0, 1);

    // ---- pre1 = deform_conv(skip1, om1) ----
    mfma_dcn<64><<<dim3(1024, 2), 256, 0, stream>>>(s1c, om1f, dcn1t, dcn1_b, pre1h, 64, 128, 128);

    // ---- final: 7x7 refpad3 concat[pre1,out2] -> 3ch fp32 NCHW + tanh ----
    mfma_conv<7, 0, 1, 16><<<dim3(1024, 1), 256, 0, stream>>>(
        pre1h, out2h, 64, 64, w3t, b3, outp, 3, 16, 128, 128, 1, 1);

    // ---- offset_sum ----
    abs_sum_kernel<<<dim3(256), 256, 0, stream>>>(om1f, 4, 27, 16384, acc + 0);
    abs_sum_kernel<<<dim3(256), 256, 0, stream>>>(om2f, 4, 27, 4096, acc + 1);
    finalize_kernel<<<dim3(1), dim3(1), 0, stream>>>(acc, outp + 196608);
}